// Round 2
// baseline (6767.805 us; speedup 1.0000x reference)
//
#include <hip/hip_runtime.h>
#include <math.h>

constexpr int BB = 64, NN = 512, DD = 128, UU = 64;
constexpr int PARTS = 8, STRIP = 64;          // 8 blocks per batch, 64-row strips
constexpr float KCOUL = 14.399645351950548f;
constexpr float NOISEF = 1e-8f;
#define M_PIF 3.14159265358979323846f

// ---------------- chi MLP: one wave (64 lanes) per row, 4 rows/block ----------
__global__ __launch_bounds__(256) void chi_kernel(
    const float* __restrict__ feats, const float* __restrict__ W1,
    const float* __restrict__ b1, const float* __restrict__ W2,
    const float* __restrict__ b2, const float* __restrict__ W3,
    const float* __restrict__ b3, float* __restrict__ chi)
{
  int wave = threadIdx.x >> 6, lane = threadIdx.x & 63;
  int row = (blockIdx.x << 2) + wave;
  __shared__ float sf[4][DD];
  __shared__ float sh[4][UU];
  const float* f = feats + (size_t)row * DD;
  sf[wave][lane] = f[lane];
  sf[wave][lane + 64] = f[lane + 64];
  __syncthreads();
  float a = b1[lane];
  #pragma unroll 8
  for (int d = 0; d < DD; ++d) a = fmaf(sf[wave][d], W1[d * UU + lane], a);
  float h1 = a - tanhf(a);            // tanhshrink
  sh[wave][lane] = h1;
  __syncthreads();
  float a2 = b2[lane];
  #pragma unroll 8
  for (int i = 0; i < UU; ++i) a2 = fmaf(sh[wave][i], W2[i * UU + lane], a2);
  float h2 = a2 - tanhf(a2);
  float prod = h2 * W3[lane];
  #pragma unroll
  for (int off = 32; off; off >>= 1) prod += __shfl_down(prod, off, 64);
  if (lane == 0) {
    float z = prod + b3[0];
    chi[row] = z - tanhf(z);
  }
}

// ---------------- build A (written straight into d_out's A region) ------------
__global__ __launch_bounds__(256) void build_A_kernel(
    const float* __restrict__ pos, const int* __restrict__ ntype,
    const float* __restrict__ hardness, const float* __restrict__ sigma,
    float* __restrict__ Aout)
{
  int b = blockIdx.y;
  int r0 = blockIdx.x * 16;
  __shared__ float px[NN], py[NN], pz[NN], s2[NN], hd[NN];
  for (int n = threadIdx.x; n < NN; n += 256) {
    const float* p = pos + ((size_t)b * NN + n) * 3;
    px[n] = p[0]; py[n] = p[1]; pz[n] = p[2];
    int ty = ntype[b * NN + n];
    float s = sigma[ty];
    s2[n] = s * s;
    hd[n] = hardness[ty];
  }
  __syncthreads();
  int c0 = (threadIdx.x & 127) << 2;
  int rsub = threadIdx.x >> 7;
  float* outB = Aout + (size_t)b * NN * NN;
  for (int k = 0; k < 8; ++k) {
    int i = r0 + (k << 1) + rsub;
    float pxi = px[i], pyi = py[i], pzi = pz[i], s2i = s2[i];
    float4 v;
    float* vp = &v.x;
    #pragma unroll
    for (int c = 0; c < 4; ++c) {
      int j = c0 + c;
      float dx = pxi - px[j], dy = pyi - py[j], dz = pzi - pz[j];
      float d = sqrtf(fmaf(dx, dx, fmaf(dy, dy, dz * dz))) + NOISEF;
      float arg = d * rsqrtf(2.0f * (s2i + s2[j]));
      float val = KCOUL * erff(arg) / d;
      if (j == i) val += hd[i] + KCOUL * rsqrtf(2.0f * M_PIF * s2i);
      vp[c] = val;
    }
    *reinterpret_cast<float4*>(outB + (size_t)i * NN + c0) = v;
  }
}

// ---------------- multi-block CG: 8 blocks/batch, per-batch spin barriers -----
__device__ __forceinline__ void bar_arrive(int* ctr) {
  __threadfence();            // release: make this block's global writes visible
  __syncthreads();            // all threads' fences done before the count bump
  if (threadIdx.x == 0) atomicAdd(ctr, 1);
}
__device__ __forceinline__ void bar_wait(int* ctr, int target) {
  if (threadIdx.x == 0) {
    while (atomicAdd(ctr, 0) < target) __builtin_amdgcn_s_sleep(2);
  }
  __syncthreads();
  __threadfence();            // acquire: invalidate stale L1 before reading peers' data
}

__global__ __launch_bounds__(256) void cg_kernel(
    const float* __restrict__ Aall, const float* __restrict__ tq,
    float* __restrict__ qout /* in: chi, out: charges */,
    float2* __restrict__ gr,  float2* __restrict__ gp,   // gp: 2 buffers
    float2* __restrict__ prr, float2* __restrict__ ppq,
    float2* __restrict__ pxs, int* __restrict__ bar)
{
  int b = blockIdx.x & 63;          // same-batch blocks land on one XCD (%8 heuristic)
  int part = blockIdx.x >> 6;
  int t = threadIdx.x;
  int i0 = part * STRIP;
  const float* A = Aall + (size_t)b * NN * NN;
  int* mybar = bar + b;
  float2* myprr = prr + b * PARTS;
  float2* myppq = ppq + b * PARTS;
  float2* mypxs = pxs + b * PARTS;
  float2* grb = gr + b * NN;

  __shared__ float2 sp[NN];                 // full p vector (both RHS)
  __shared__ float4 sacc[2][16][16];        // [rhs][jrow][i4] matvec partials
  __shared__ float2 sq[STRIP], sr[STRIP], sx[STRIP];

  // ---- init: r = p-seed = rhs, x = 0 ----
  if (t < STRIP) {
    float c = qout[b * NN + i0 + t];        // chi
    float2 rv = make_float2(-c, 1.0f);
    sr[t] = rv;
    sx[t] = make_float2(0.f, 0.f);
    grb[i0 + t] = rv;
    float2 dv = make_float2(rv.x * rv.x, rv.y * rv.y);
    #pragma unroll
    for (int off = 32; off; off >>= 1) {
      dv.x += __shfl_down(dv.x, off, 64);
      dv.y += __shfl_down(dv.y, off, 64);
    }
    if (t == 0) myprr[part] = dv;
  }
  bar_arrive(mybar);

  float2 rr0 = make_float2(0.f, 0.f), rr = rr0, rrprev = rr0;
  float tol0 = 0.f, tol1 = 0.f;
  int k = 0;
  while (true) {
    // ---- phase M: global rr, convergence, p-recurrence, matvec, p.q ----
    bar_wait(mybar, PARTS * (2 * k + 1));
    rr = make_float2(0.f, 0.f);
    #pragma unroll
    for (int g = 0; g < PARTS; ++g) { float2 v = myprr[g]; rr.x += v.x; rr.y += v.y; }
    if (k == 0) {
      rr0 = rr;
      tol0 = fmaxf(1e-10f * rr0.x, 1e-12f);
      tol1 = fmaxf(1e-10f * rr0.y, 1e-12f);
    }
    bool act0 = rr.x > tol0, act1 = rr.y > tol1;
    if ((!act0 && !act1) || k >= 64) break;

    float be0 = (k && act0) ? rr.x / rrprev.x : 0.f;
    float be1 = (k && act1) ? rr.y / rrprev.y : 0.f;
    rrprev = rr;
    float2* gpcur = gp + (size_t)(k & 1) * BB * NN + b * NN;
    float2* gpold = gp + (size_t)((k & 1) ^ 1) * BB * NN + b * NN;
    #pragma unroll
    for (int j = t; j < NN; j += 256) {     // redundant full-p recurrence (cheap)
      float2 rj = grb[j];
      float2 pj;
      if (k == 0) pj = rj;
      else {
        float2 po = gpold[j];
        pj = make_float2(fmaf(be0, po.x, rj.x), fmaf(be1, po.y, rj.y));
      }
      sp[j] = pj;
      if (j >= i0 && j < i0 + STRIP) gpcur[j] = pj;   // owner publishes its strip
    }
    __syncthreads();

    // matvec: q[i] = sum_j A[j][i] p[j], float4 over i, 16 j-groups
    {
      int i4 = t & 15, jr = t >> 4;
      const float* ap = A + (size_t)(jr * 32) * NN + i0 + i4 * 4;
      float4 a0 = make_float4(0.f, 0.f, 0.f, 0.f);
      float4 a1 = a0;
      #pragma unroll 4
      for (int m = 0; m < 32; ++m) {
        float4 av = *reinterpret_cast<const float4*>(ap);
        ap += NN;
        float2 pj = sp[jr * 32 + m];
        a0.x = fmaf(av.x, pj.x, a0.x); a0.y = fmaf(av.y, pj.x, a0.y);
        a0.z = fmaf(av.z, pj.x, a0.z); a0.w = fmaf(av.w, pj.x, a0.w);
        a1.x = fmaf(av.x, pj.y, a1.x); a1.y = fmaf(av.y, pj.y, a1.y);
        a1.z = fmaf(av.z, pj.y, a1.z); a1.w = fmaf(av.w, pj.y, a1.w);
      }
      sacc[0][jr][i4] = a0;
      sacc[1][jr][i4] = a1;
    }
    __syncthreads();
    if (t < 32) {                            // fold 16 j-groups
      int rhs = t >> 4, i4 = t & 15;
      float4 s = sacc[rhs][0][i4];
      #pragma unroll
      for (int g = 1; g < 16; ++g) {
        float4 v = sacc[rhs][g][i4];
        s.x += v.x; s.y += v.y; s.z += v.z; s.w += v.w;
      }
      float* dst = reinterpret_cast<float*>(sq);
      const float* sv = reinterpret_cast<const float*>(&s);
      #pragma unroll
      for (int c = 0; c < 4; ++c) dst[(i4 * 4 + c) * 2 + rhs] = sv[c];
    }
    __syncthreads();
    if (t < STRIP) {                         // partial p.q over strip
      float2 pv = sp[i0 + t], qv = sq[t];
      float2 dv = make_float2(pv.x * qv.x, pv.y * qv.y);
      #pragma unroll
      for (int off = 32; off; off >>= 1) {
        dv.x += __shfl_down(dv.x, off, 64);
        dv.y += __shfl_down(dv.y, off, 64);
      }
      if (t == 0) myppq[part] = dv;
    }
    bar_arrive(mybar);

    // ---- phase U: alpha, x/r update, new rr partial ----
    bar_wait(mybar, PARTS * (2 * k + 2));
    float2 pq = make_float2(0.f, 0.f);
    #pragma unroll
    for (int g = 0; g < PARTS; ++g) { float2 v = myppq[g]; pq.x += v.x; pq.y += v.y; }
    float al0 = act0 ? rr.x / pq.x : 0.f;
    float al1 = act1 ? rr.y / pq.y : 0.f;
    if (t < STRIP) {
      float2 pv = sp[i0 + t], qv = sq[t];
      float2 xv = sx[t], rv = sr[t];
      xv.x = fmaf(al0, pv.x, xv.x);  xv.y = fmaf(al1, pv.y, xv.y);
      rv.x = fmaf(-al0, qv.x, rv.x); rv.y = fmaf(-al1, qv.y, rv.y);
      sx[t] = xv; sr[t] = rv;
      grb[i0 + t] = rv;
      float2 dv = make_float2(rv.x * rv.x, rv.y * rv.y);
      #pragma unroll
      for (int off = 32; off; off >>= 1) {
        dv.x += __shfl_down(dv.x, off, 64);
        dv.y += __shfl_down(dv.y, off, 64);
      }
      if (t == 0) myprr[part] = dv;
    }
    bar_arrive(mybar);
    ++k;
  }

  // ---- epilogue: lambda = (1'y - Q)/(1'z); charges = y - lambda*z ----
  if (t < STRIP) {
    float2 dv = sx[t];
    #pragma unroll
    for (int off = 32; off; off >>= 1) {
      dv.x += __shfl_down(dv.x, off, 64);
      dv.y += __shfl_down(dv.y, off, 64);
    }
    if (t == 0) mypxs[part] = dv;
  }
  bar_arrive(mybar);                              // -> PARTS*(2k+2)
  bar_wait(mybar, PARTS * (2 * k + 2));
  if (t < STRIP) {
    float2 s = make_float2(0.f, 0.f);
    #pragma unroll
    for (int g = 0; g < PARTS; ++g) { float2 v = mypxs[g]; s.x += v.x; s.y += v.y; }
    float lam = (s.x - tq[b]) / s.y;
    float2 xv = sx[t];
    qout[b * NN + i0 + t] = xv.x - lam * xv.y;
  }
}

extern "C" void kernel_launch(void* const* d_in, const int* in_sizes, int n_in,
                              void* d_out, int out_size, void* d_ws, size_t ws_size,
                              hipStream_t stream) {
  const float* pos      = (const float*)d_in[0];
  const float* feats    = (const float*)d_in[1];
  const int*   ntype    = (const int*)  d_in[2];
  const float* tq       = (const float*)d_in[3];
  const float* hardness = (const float*)d_in[4];
  const float* sigma    = (const float*)d_in[5];
  const float* W1 = (const float*)d_in[6];
  const float* b1 = (const float*)d_in[7];
  const float* W2 = (const float*)d_in[8];
  const float* b2 = (const float*)d_in[9];
  const float* W3 = (const float*)d_in[10];
  const float* b3 = (const float*)d_in[11];

  float* out  = (float*)d_out;
  float* chi  = out;             // charges region doubles as chi scratch
  float* Aout = out + BB * NN;   // output 1: A, batch-major

  // workspace layout (d_ws poisoned 0xAA each launch -> zero the barrier region)
  char* ws = (char*)d_ws;
  int*    bar  = (int*)   (ws + 0);        // 64 ints
  float2* prr  = (float2*)(ws + 512);      // 64*8
  float2* ppq  = (float2*)(ws + 512 + 4096);
  float2* pxs  = (float2*)(ws + 512 + 8192);
  float2* gr   = (float2*)(ws + 16384);                    // 256 KB
  float2* gp   = (float2*)(ws + 16384 + BB * NN * 8);      // 2 x 256 KB

  hipMemsetAsync(bar, 0, 64 * sizeof(int), stream);
  chi_kernel<<<dim3(BB * NN / 4), dim3(256), 0, stream>>>(feats, W1, b1, W2, b2, W3, b3, chi);
  build_A_kernel<<<dim3(NN / 16, BB), dim3(256), 0, stream>>>(pos, ntype, hardness, sigma, Aout);

  void* args[] = {(void*)&Aout, (void*)&tq, (void*)&out, (void*)&gr, (void*)&gp,
                  (void*)&prr, (void*)&ppq, (void*)&pxs, (void*)&bar};
  hipLaunchCooperativeKernel((const void*)cg_kernel, dim3(BB * PARTS), dim3(256),
                             args, 0, stream);
}

// Round 3
// 614.960 us; speedup vs baseline: 11.0053x; 11.0053x over previous
//
#include <hip/hip_runtime.h>
#include <math.h>

constexpr int BB = 64, NN = 512, DD = 128, UU = 64;
constexpr float KCOUL = 14.399645351950548f;
constexpr float NOISEF = 1e-8f;
#define M_PIF 3.14159265358979323846f

// ---------------- chi MLP: one wave (64 lanes) per row, 4 rows/block ----------
__global__ __launch_bounds__(256) void chi_kernel(
    const float* __restrict__ feats, const float* __restrict__ W1,
    const float* __restrict__ b1, const float* __restrict__ W2,
    const float* __restrict__ b2, const float* __restrict__ W3,
    const float* __restrict__ b3, float* __restrict__ chi)
{
  int wave = threadIdx.x >> 6, lane = threadIdx.x & 63;
  int row = (blockIdx.x << 2) + wave;
  __shared__ float sf[4][DD];
  __shared__ float sh[4][UU];
  const float* f = feats + (size_t)row * DD;
  sf[wave][lane] = f[lane];
  sf[wave][lane + 64] = f[lane + 64];
  __syncthreads();
  float a = b1[lane];
  #pragma unroll 8
  for (int d = 0; d < DD; ++d) a = fmaf(sf[wave][d], W1[d * UU + lane], a);
  float h1 = a - tanhf(a);            // tanhshrink
  sh[wave][lane] = h1;
  __syncthreads();
  float a2 = b2[lane];
  #pragma unroll 8
  for (int i = 0; i < UU; ++i) a2 = fmaf(sh[wave][i], W2[i * UU + lane], a2);
  float h2 = a2 - tanhf(a2);
  float prod = h2 * W3[lane];
  #pragma unroll
  for (int off = 32; off; off >>= 1) prod += __shfl_down(prod, off, 64);
  if (lane == 0) {
    float z = prod + b3[0];
    chi[row] = z - tanhf(z);
  }
}

// ---------------- build A (written straight into d_out's A region) ------------
__global__ __launch_bounds__(256) void build_A_kernel(
    const float* __restrict__ pos, const int* __restrict__ ntype,
    const float* __restrict__ hardness, const float* __restrict__ sigma,
    float* __restrict__ Aout)
{
  int b = blockIdx.y;
  int r0 = blockIdx.x * 16;
  __shared__ float px[NN], py[NN], pz[NN], s2[NN], hd[NN];
  for (int n = threadIdx.x; n < NN; n += 256) {
    const float* p = pos + ((size_t)b * NN + n) * 3;
    px[n] = p[0]; py[n] = p[1]; pz[n] = p[2];
    int ty = ntype[b * NN + n];
    float s = sigma[ty];
    s2[n] = s * s;
    hd[n] = hardness[ty];
  }
  __syncthreads();
  int c0 = (threadIdx.x & 127) << 2;
  int rsub = threadIdx.x >> 7;
  float* outB = Aout + (size_t)b * NN * NN;
  for (int k = 0; k < 8; ++k) {
    int i = r0 + (k << 1) + rsub;
    float pxi = px[i], pyi = py[i], pzi = pz[i], s2i = s2[i];
    float4 v;
    float* vp = &v.x;
    #pragma unroll
    for (int c = 0; c < 4; ++c) {
      int j = c0 + c;
      float dx = pxi - px[j], dy = pyi - py[j], dz = pzi - pz[j];
      float d = sqrtf(fmaf(dx, dx, fmaf(dy, dy, dz * dz))) + NOISEF;
      float arg = d * rsqrtf(2.0f * (s2i + s2[j]));
      float val = KCOUL * erff(arg) / d;
      if (j == i) val += hd[i] + KCOUL * rsqrtf(2.0f * M_PIF * s2i);
      vp[c] = val;
    }
    *reinterpret_cast<float4*>(outB + (size_t)i * NN + c0) = v;
  }
}

// ---------------- batched 2-RHS CG, one 1024-thread block per batch -----------
__device__ __forceinline__ float2 blockReduce2(float2 v, float2* wred, int t) {
  #pragma unroll
  for (int off = 32; off; off >>= 1) {
    v.x += __shfl_down(v.x, off, 64);
    v.y += __shfl_down(v.y, off, 64);
  }
  __syncthreads();                       // protects wred reuse; also fences LDS
  if ((t & 63) == 0) wred[t >> 6] = v;
  __syncthreads();
  float2 r = wred[0];
  #pragma unroll
  for (int k = 1; k < 16; ++k) { r.x += wred[k].x; r.y += wred[k].y; }
  return r;                              // identical in all threads
}

__global__ __launch_bounds__(1024) void cg_kernel(
    const float* __restrict__ Aall, const float* __restrict__ tq,
    float* __restrict__ qout /* in: chi, out: charges */)
{
  int b = blockIdx.x;
  const float* A = Aall + (size_t)b * NN * NN;
  int t = threadIdx.x;
  __shared__ float2 p01[NN], q01[NN], r01[NN], x01[NN];
  __shared__ float4 sacc0[8][128];        // [row-group][col4] rhs0 partials
  __shared__ float4 sacc1[8][128];        // rhs1 partials
  __shared__ float2 wred[16];

  float2 z2 = make_float2(0.f, 0.f);
  float2 rsq = z2;
  if (t < NN) {
    float b0 = -qout[b * NN + t];        // rhs0 = -chi ; rhs1 = ones
    x01[t] = z2;
    r01[t] = make_float2(b0, 1.0f);
    p01[t] = make_float2(b0, 1.0f);
    rsq = make_float2(b0 * b0, 1.0f);
  }
  float2 rr = blockReduce2(rsq, wred, t);   // also makes p01 visible
  float tol0 = fmaxf(1e-10f * rr.x, 1e-12f);  // rel 1e-5 with abs floor
  float tol1 = fmaxf(1e-10f * rr.y, 1e-12f);

  const int c4 = (t & 127) << 2;          // 4 consecutive columns
  const int jr = t >> 7;                  // row group (0..7), 64 rows each

  for (int it = 0; it < 120; ++it) {
    bool act0 = rr.x > tol0, act1 = rr.y > tol1;
    if (!act0 && !act1) break;

    // ---- matvec q = A^T p (== A p by symmetry): float4 column scan ----
    {
      const float* ap = A + (size_t)(jr * 64) * NN + c4;
      float4 a0 = make_float4(0.f, 0.f, 0.f, 0.f);
      float4 a1 = a0;
      #pragma unroll 8
      for (int m = 0; m < 64; ++m) {
        float4 av = *reinterpret_cast<const float4*>(ap);
        ap += NN;
        float2 pj = p01[jr * 64 + m];     // LDS broadcast
        a0.x = fmaf(av.x, pj.x, a0.x); a0.y = fmaf(av.y, pj.x, a0.y);
        a0.z = fmaf(av.z, pj.x, a0.z); a0.w = fmaf(av.w, pj.x, a0.w);
        a1.x = fmaf(av.x, pj.y, a1.x); a1.y = fmaf(av.y, pj.y, a1.y);
        a1.z = fmaf(av.z, pj.y, a1.z); a1.w = fmaf(av.w, pj.y, a1.w);
      }
      sacc0[jr][t & 127] = a0;
      sacc1[jr][t & 127] = a1;
    }
    __syncthreads();
    float2 dv = z2;
    if (t < NN) {                          // fold 8 row-groups -> q[i]
      const float* f0 = reinterpret_cast<const float*>(sacc0);
      const float* f1 = reinterpret_cast<const float*>(sacc1);
      float s0 = 0.f, s1 = 0.f;
      #pragma unroll
      for (int g = 0; g < 8; ++g) {        // addr g*512 + t : conflict-free
        s0 += f0[g * 512 + t];
        s1 += f1[g * 512 + t];
      }
      q01[t] = make_float2(s0, s1);
      float2 pv = p01[t];
      dv.x = s0 * pv.x;
      dv.y = s1 * pv.y;
    }
    float2 pq = blockReduce2(dv, wred, t);
    float al0 = act0 ? rr.x / pq.x : 0.f;
    float al1 = act1 ? rr.y / pq.y : 0.f;
    float2 rn = z2;
    if (t < NN) {
      float2 xv = x01[t], rv = r01[t], pv = p01[t], qv = q01[t];
      xv.x = fmaf(al0, pv.x, xv.x);  xv.y = fmaf(al1, pv.y, xv.y);
      rv.x = fmaf(-al0, qv.x, rv.x); rv.y = fmaf(-al1, qv.y, rv.y);
      x01[t] = xv; r01[t] = rv;
      rn.x = rv.x * rv.x; rn.y = rv.y * rv.y;
    }
    float2 rrn = blockReduce2(rn, wred, t);
    float be0 = act0 ? rrn.x / rr.x : 0.f;
    float be1 = act1 ? rrn.y / rr.y : 0.f;
    if (t < NN) {
      float2 rv = r01[t], pv = p01[t];
      pv.x = fmaf(be0, pv.x, rv.x);
      pv.y = fmaf(be1, pv.y, rv.y);
      p01[t] = pv;
    }
    rr = rrn;
    __syncthreads();                      // p01/sacc ready for next matvec
  }

  // ---- epilogue: lambda = (1'y - Q)/(1'z); charges = y - lambda*z ----
  float2 sv = z2;
  if (t < NN) sv = x01[t];
  float2 s = blockReduce2(sv, wred, t);
  float lam = (s.x - tq[b]) / s.y;
  if (t < NN) qout[b * NN + t] = x01[t].x - lam * x01[t].y;
}

extern "C" void kernel_launch(void* const* d_in, const int* in_sizes, int n_in,
                              void* d_out, int out_size, void* d_ws, size_t ws_size,
                              hipStream_t stream) {
  const float* pos      = (const float*)d_in[0];
  const float* feats    = (const float*)d_in[1];
  const int*   ntype    = (const int*)  d_in[2];
  const float* tq       = (const float*)d_in[3];
  const float* hardness = (const float*)d_in[4];
  const float* sigma    = (const float*)d_in[5];
  const float* W1 = (const float*)d_in[6];
  const float* b1 = (const float*)d_in[7];
  const float* W2 = (const float*)d_in[8];
  const float* b2 = (const float*)d_in[9];
  const float* W3 = (const float*)d_in[10];
  const float* b3 = (const float*)d_in[11];

  float* out  = (float*)d_out;
  float* chi  = out;             // charges region doubles as chi scratch
  float* Aout = out + BB * NN;   // output 1: A, batch-major

  chi_kernel<<<dim3(BB * NN / 4), dim3(256), 0, stream>>>(feats, W1, b1, W2, b2, W3, b3, chi);
  build_A_kernel<<<dim3(NN / 16, BB), dim3(256), 0, stream>>>(pos, ntype, hardness, sigma, Aout);
  cg_kernel<<<dim3(BB), dim3(1024), 0, stream>>>(Aout, tq, chi);
}

// Round 4
// 349.252 us; speedup vs baseline: 19.3780x; 1.7608x over previous
//
#include <hip/hip_runtime.h>
#include <math.h>

constexpr int BB = 64, NN = 512, DD = 128, UU = 64;
constexpr float KCOUL = 14.399645351950548f;
constexpr float NOISEF = 1e-8f;
#define M_PIF 3.14159265358979323846f

__device__ __forceinline__ unsigned short f2bf(float f) {   // RNE float->bf16
  unsigned int u = __float_as_uint(f);
  u += 0x7fffu + ((u >> 16) & 1u);
  return (unsigned short)(u >> 16);
}

// ---------------- chi MLP: one wave (64 lanes) per row, 4 rows/block ----------
__global__ __launch_bounds__(256) void chi_kernel(
    const float* __restrict__ feats, const float* __restrict__ W1,
    const float* __restrict__ b1, const float* __restrict__ W2,
    const float* __restrict__ b2, const float* __restrict__ W3,
    const float* __restrict__ b3, float* __restrict__ chi)
{
  int wave = threadIdx.x >> 6, lane = threadIdx.x & 63;
  int row = (blockIdx.x << 2) + wave;
  __shared__ float sf[4][DD];
  __shared__ float sh[4][UU];
  const float* f = feats + (size_t)row * DD;
  sf[wave][lane] = f[lane];
  sf[wave][lane + 64] = f[lane + 64];
  __syncthreads();
  float a = b1[lane];
  #pragma unroll 8
  for (int d = 0; d < DD; ++d) a = fmaf(sf[wave][d], W1[d * UU + lane], a);
  float h1 = a - tanhf(a);            // tanhshrink
  sh[wave][lane] = h1;
  __syncthreads();
  float a2 = b2[lane];
  #pragma unroll 8
  for (int i = 0; i < UU; ++i) a2 = fmaf(sh[wave][i], W2[i * UU + lane], a2);
  float h2 = a2 - tanhf(a2);
  float prod = h2 * W3[lane];
  #pragma unroll
  for (int off = 32; off; off >>= 1) prod += __shfl_down(prod, off, 64);
  if (lane == 0) {
    float z = prod + b3[0];
    chi[row] = z - tanhf(z);
  }
}

// ------------- build A (fp32 to d_out) + optional bf16 copy (to ws) ----------
__global__ __launch_bounds__(256) void build_A_kernel(
    const float* __restrict__ pos, const int* __restrict__ ntype,
    const float* __restrict__ hardness, const float* __restrict__ sigma,
    float* __restrict__ Aout, unsigned short* __restrict__ Abf)
{
  int b = blockIdx.y;
  int r0 = blockIdx.x * 16;
  __shared__ float px[NN], py[NN], pz[NN], s2[NN], hd[NN];
  for (int n = threadIdx.x; n < NN; n += 256) {
    const float* p = pos + ((size_t)b * NN + n) * 3;
    px[n] = p[0]; py[n] = p[1]; pz[n] = p[2];
    int ty = ntype[b * NN + n];
    float s = sigma[ty];
    s2[n] = s * s;
    hd[n] = hardness[ty];
  }
  __syncthreads();
  int c0 = (threadIdx.x & 127) << 2;
  int rsub = threadIdx.x >> 7;
  float* outB = Aout + (size_t)b * NN * NN;
  unsigned short* bfB = Abf ? Abf + (size_t)b * NN * NN : nullptr;
  for (int k = 0; k < 8; ++k) {
    int i = r0 + (k << 1) + rsub;
    float pxi = px[i], pyi = py[i], pzi = pz[i], s2i = s2[i];
    float4 v;
    float* vp = &v.x;
    #pragma unroll
    for (int c = 0; c < 4; ++c) {
      int j = c0 + c;
      float dx = pxi - px[j], dy = pyi - py[j], dz = pzi - pz[j];
      float d = sqrtf(fmaf(dx, dx, fmaf(dy, dy, dz * dz))) + NOISEF;
      float arg = d * rsqrtf(2.0f * (s2i + s2[j]));
      float val = KCOUL * erff(arg) / d;
      if (j == i) val += hd[i] + KCOUL * rsqrtf(2.0f * M_PIF * s2i);
      vp[c] = val;
    }
    *reinterpret_cast<float4*>(outB + (size_t)i * NN + c0) = v;
    if (bfB) {
      ushort4 w;
      w.x = f2bf(v.x); w.y = f2bf(v.y); w.z = f2bf(v.z); w.w = f2bf(v.w);
      *reinterpret_cast<ushort4*>(bfB + (size_t)i * NN + c0) = w;
    }
  }
}

// ---------------- shared reduction helper ------------------------------------
__device__ __forceinline__ float2 blockReduce2(float2 v, float2* wred, int t) {
  #pragma unroll
  for (int off = 32; off; off >>= 1) {
    v.x += __shfl_down(v.x, off, 64);
    v.y += __shfl_down(v.y, off, 64);
  }
  __syncthreads();
  if ((t & 63) == 0) wred[t >> 6] = v;
  __syncthreads();
  float2 r = wred[0];
  #pragma unroll
  for (int k = 1; k < 16; ++k) { r.x += wred[k].x; r.y += wred[k].y; }
  return r;
}

// ------------- bf16-matvec 2-RHS CG, one 1024-thread block per batch ---------
__global__ __launch_bounds__(1024) void cg_kernel_bf(
    const unsigned short* __restrict__ Abf, const float* __restrict__ tq,
    float* __restrict__ qout /* in: chi, out: charges */)
{
  int b = blockIdx.x;
  const unsigned short* A = Abf + (size_t)b * NN * NN;
  int t = threadIdx.x;
  __shared__ float2 p01[NN], q01[NN], r01[NN], x01[NN];
  __shared__ float sacc0[16][NN];          // 32 KB  rhs0 partials
  __shared__ float sacc1[16][NN];          // 32 KB  rhs1 partials
  __shared__ float2 wred[16];

  float2 z2 = make_float2(0.f, 0.f);
  float2 rsq = z2;
  if (t < NN) {
    float b0 = -qout[b * NN + t];          // rhs0 = -chi ; rhs1 = ones
    x01[t] = z2;
    r01[t] = make_float2(b0, 1.0f);
    p01[t] = make_float2(b0, 1.0f);
    rsq = make_float2(b0 * b0, 1.0f);
  }
  float2 rr = blockReduce2(rsq, wred, t);  // also publishes p01
  float tol0 = fmaxf(1e-6f * rr.x, 1e-12f);   // rel residual 1e-3
  float tol1 = fmaxf(1e-6f * rr.y, 1e-12f);

  const int ow = t & 63;                   // column owner: 8 consecutive cols
  const int jr = t >> 6;                   // row group 0..15, 32 rows each
  const unsigned short* baseA = A + (size_t)(jr * 32) * NN + ow * 8;

  for (int it = 0; it < 48; ++it) {
    bool act0 = rr.x > tol0, act1 = rr.y > tol1;
    if (!act0 && !act1) break;

    // ---- matvec q = A p (A symmetric): bf16 column scan, 2 row-streams ----
    float aA0[8] = {0,0,0,0,0,0,0,0}, aA1[8] = {0,0,0,0,0,0,0,0};
    float aB0[8] = {0,0,0,0,0,0,0,0}, aB1[8] = {0,0,0,0,0,0,0,0};
    const unsigned short* apA = baseA;
    const unsigned short* apB = baseA + 16 * NN;
    const int pb = jr * 32;
    #pragma unroll 4
    for (int m = 0; m < 16; ++m) {
      uint4 ua = *reinterpret_cast<const uint4*>(apA);
      uint4 ub = *reinterpret_cast<const uint4*>(apB);
      apA += NN; apB += NN;
      float2 pA = p01[pb + m];
      float2 pB = p01[pb + 16 + m];
      float fa[8], fb[8];
      fa[0] = __uint_as_float(ua.x << 16); fa[1] = __uint_as_float(ua.x & 0xffff0000u);
      fa[2] = __uint_as_float(ua.y << 16); fa[3] = __uint_as_float(ua.y & 0xffff0000u);
      fa[4] = __uint_as_float(ua.z << 16); fa[5] = __uint_as_float(ua.z & 0xffff0000u);
      fa[6] = __uint_as_float(ua.w << 16); fa[7] = __uint_as_float(ua.w & 0xffff0000u);
      fb[0] = __uint_as_float(ub.x << 16); fb[1] = __uint_as_float(ub.x & 0xffff0000u);
      fb[2] = __uint_as_float(ub.y << 16); fb[3] = __uint_as_float(ub.y & 0xffff0000u);
      fb[4] = __uint_as_float(ub.z << 16); fb[5] = __uint_as_float(ub.z & 0xffff0000u);
      fb[6] = __uint_as_float(ub.w << 16); fb[7] = __uint_as_float(ub.w & 0xffff0000u);
      #pragma unroll
      for (int k2 = 0; k2 < 8; ++k2) {
        aA0[k2] = fmaf(fa[k2], pA.x, aA0[k2]);
        aA1[k2] = fmaf(fa[k2], pA.y, aA1[k2]);
        aB0[k2] = fmaf(fb[k2], pB.x, aB0[k2]);
        aB1[k2] = fmaf(fb[k2], pB.y, aB1[k2]);
      }
    }
    {
      float4 v;
      v.x = aA0[0] + aB0[0]; v.y = aA0[1] + aB0[1];
      v.z = aA0[2] + aB0[2]; v.w = aA0[3] + aB0[3];
      *reinterpret_cast<float4*>(&sacc0[jr][ow * 8]) = v;
      v.x = aA0[4] + aB0[4]; v.y = aA0[5] + aB0[5];
      v.z = aA0[6] + aB0[6]; v.w = aA0[7] + aB0[7];
      *reinterpret_cast<float4*>(&sacc0[jr][ow * 8 + 4]) = v;
      v.x = aA1[0] + aB1[0]; v.y = aA1[1] + aB1[1];
      v.z = aA1[2] + aB1[2]; v.w = aA1[3] + aB1[3];
      *reinterpret_cast<float4*>(&sacc1[jr][ow * 8]) = v;
      v.x = aA1[4] + aB1[4]; v.y = aA1[5] + aB1[5];
      v.z = aA1[6] + aB1[6]; v.w = aA1[7] + aB1[7];
      *reinterpret_cast<float4*>(&sacc1[jr][ow * 8 + 4]) = v;
    }
    __syncthreads();
    float2 dv = z2;
    if (t < NN) {                           // fold 16 row-groups -> q[i]
      float s0 = 0.f, s1 = 0.f;
      #pragma unroll
      for (int g = 0; g < 16; ++g) { s0 += sacc0[g][t]; s1 += sacc1[g][t]; }
      q01[t] = make_float2(s0, s1);
      float2 pv = p01[t];
      dv.x = s0 * pv.x;
      dv.y = s1 * pv.y;
    }
    float2 pq = blockReduce2(dv, wred, t);
    float al0 = act0 ? rr.x / pq.x : 0.f;
    float al1 = act1 ? rr.y / pq.y : 0.f;
    float2 rn = z2;
    if (t < NN) {
      float2 xv = x01[t], rv = r01[t], pv = p01[t], qv = q01[t];
      xv.x = fmaf(al0, pv.x, xv.x);  xv.y = fmaf(al1, pv.y, xv.y);
      rv.x = fmaf(-al0, qv.x, rv.x); rv.y = fmaf(-al1, qv.y, rv.y);
      x01[t] = xv; r01[t] = rv;
      rn.x = rv.x * rv.x; rn.y = rv.y * rv.y;
    }
    float2 rrn = blockReduce2(rn, wred, t);
    float be0 = act0 ? rrn.x / rr.x : 0.f;
    float be1 = act1 ? rrn.y / rr.y : 0.f;
    if (t < NN) {
      float2 rv = r01[t], pv = p01[t];
      pv.x = fmaf(be0, pv.x, rv.x);
      pv.y = fmaf(be1, pv.y, rv.y);
      p01[t] = pv;
    }
    rr = rrn;
    __syncthreads();                        // p01/sacc safe for next iteration
  }

  float2 sv = z2;
  if (t < NN) sv = x01[t];
  float2 s = blockReduce2(sv, wred, t);
  float lam = (s.x - tq[b]) / s.y;
  if (t < NN) qout[b * NN + t] = x01[t].x - lam * x01[t].y;
}

// ---------------- fp32 fallback (round-3 structure, looser tol) --------------
__global__ __launch_bounds__(1024) void cg_kernel_f32(
    const float* __restrict__ Aall, const float* __restrict__ tq,
    float* __restrict__ qout)
{
  int b = blockIdx.x;
  const float* A = Aall + (size_t)b * NN * NN;
  int t = threadIdx.x;
  __shared__ float2 p01[NN], q01[NN], r01[NN], x01[NN];
  __shared__ float4 sacc0[8][128];
  __shared__ float4 sacc1[8][128];
  __shared__ float2 wred[16];

  float2 z2 = make_float2(0.f, 0.f);
  float2 rsq = z2;
  if (t < NN) {
    float b0 = -qout[b * NN + t];
    x01[t] = z2;
    r01[t] = make_float2(b0, 1.0f);
    p01[t] = make_float2(b0, 1.0f);
    rsq = make_float2(b0 * b0, 1.0f);
  }
  float2 rr = blockReduce2(rsq, wred, t);
  float tol0 = fmaxf(1e-6f * rr.x, 1e-12f);
  float tol1 = fmaxf(1e-6f * rr.y, 1e-12f);
  const int c4 = (t & 127) << 2;
  const int jr = t >> 7;
  for (int it = 0; it < 48; ++it) {
    bool act0 = rr.x > tol0, act1 = rr.y > tol1;
    if (!act0 && !act1) break;
    {
      const float* ap = A + (size_t)(jr * 64) * NN + c4;
      float4 a0 = make_float4(0.f, 0.f, 0.f, 0.f);
      float4 a1 = a0;
      #pragma unroll 8
      for (int m = 0; m < 64; ++m) {
        float4 av = *reinterpret_cast<const float4*>(ap);
        ap += NN;
        float2 pj = p01[jr * 64 + m];
        a0.x = fmaf(av.x, pj.x, a0.x); a0.y = fmaf(av.y, pj.x, a0.y);
        a0.z = fmaf(av.z, pj.x, a0.z); a0.w = fmaf(av.w, pj.x, a0.w);
        a1.x = fmaf(av.x, pj.y, a1.x); a1.y = fmaf(av.y, pj.y, a1.y);
        a1.z = fmaf(av.z, pj.y, a1.z); a1.w = fmaf(av.w, pj.y, a1.w);
      }
      sacc0[jr][t & 127] = a0;
      sacc1[jr][t & 127] = a1;
    }
    __syncthreads();
    float2 dv = z2;
    if (t < NN) {
      const float* f0 = reinterpret_cast<const float*>(sacc0);
      const float* f1 = reinterpret_cast<const float*>(sacc1);
      float s0 = 0.f, s1 = 0.f;
      #pragma unroll
      for (int g = 0; g < 8; ++g) { s0 += f0[g * 512 + t]; s1 += f1[g * 512 + t]; }
      q01[t] = make_float2(s0, s1);
      float2 pv = p01[t];
      dv.x = s0 * pv.x; dv.y = s1 * pv.y;
    }
    float2 pq = blockReduce2(dv, wred, t);
    float al0 = act0 ? rr.x / pq.x : 0.f;
    float al1 = act1 ? rr.y / pq.y : 0.f;
    float2 rn = z2;
    if (t < NN) {
      float2 xv = x01[t], rv = r01[t], pv = p01[t], qv = q01[t];
      xv.x = fmaf(al0, pv.x, xv.x);  xv.y = fmaf(al1, pv.y, xv.y);
      rv.x = fmaf(-al0, qv.x, rv.x); rv.y = fmaf(-al1, qv.y, rv.y);
      x01[t] = xv; r01[t] = rv;
      rn.x = rv.x * rv.x; rn.y = rv.y * rv.y;
    }
    float2 rrn = blockReduce2(rn, wred, t);
    float be0 = act0 ? rrn.x / rr.x : 0.f;
    float be1 = act1 ? rrn.y / rr.y : 0.f;
    if (t < NN) {
      float2 rv = r01[t], pv = p01[t];
      pv.x = fmaf(be0, pv.x, rv.x);
      pv.y = fmaf(be1, pv.y, rv.y);
      p01[t] = pv;
    }
    rr = rrn;
    __syncthreads();
  }
  float2 sv = z2;
  if (t < NN) sv = x01[t];
  float2 s = blockReduce2(sv, wred, t);
  float lam = (s.x - tq[b]) / s.y;
  if (t < NN) qout[b * NN + t] = x01[t].x - lam * x01[t].y;
}

extern "C" void kernel_launch(void* const* d_in, const int* in_sizes, int n_in,
                              void* d_out, int out_size, void* d_ws, size_t ws_size,
                              hipStream_t stream) {
  const float* pos      = (const float*)d_in[0];
  const float* feats    = (const float*)d_in[1];
  const int*   ntype    = (const int*)  d_in[2];
  const float* tq       = (const float*)d_in[3];
  const float* hardness = (const float*)d_in[4];
  const float* sigma    = (const float*)d_in[5];
  const float* W1 = (const float*)d_in[6];
  const float* b1 = (const float*)d_in[7];
  const float* W2 = (const float*)d_in[8];
  const float* b2 = (const float*)d_in[9];
  const float* W3 = (const float*)d_in[10];
  const float* b3 = (const float*)d_in[11];

  float* out  = (float*)d_out;
  float* chi  = out;             // charges region doubles as chi scratch
  float* Aout = out + BB * NN;   // output 1: A, batch-major

  const size_t bf_bytes = (size_t)BB * NN * NN * sizeof(unsigned short);
  const bool use_bf = ws_size >= bf_bytes;
  unsigned short* Abf = use_bf ? (unsigned short*)d_ws : nullptr;

  chi_kernel<<<dim3(BB * NN / 4), dim3(256), 0, stream>>>(feats, W1, b1, W2, b2, W3, b3, chi);
  build_A_kernel<<<dim3(NN / 16, BB), dim3(256), 0, stream>>>(pos, ntype, hardness, sigma, Aout, Abf);
  if (use_bf)
    cg_kernel_bf<<<dim3(BB), dim3(1024), 0, stream>>>(Abf, tq, chi);
  else
    cg_kernel_f32<<<dim3(BB), dim3(1024), 0, stream>>>(Aout, tq, chi);
}